// Round 4
// baseline (233.372 us; speedup 1.0000x reference)
//
#include <hip/hip_runtime.h>

#define Bsz 64
#define Nn  256
#define Ee  20   // atom embedding dim
#define Dd  25   // gaussian centers

using short8  = __attribute__((ext_vector_type(8))) short;  // 8 bf16 (4 VGPRs)
using floatx4 = __attribute__((ext_vector_type(4))) float;  // 4 fp32 acc

#if __has_builtin(__builtin_amdgcn_exp2f)
#define EXP2F(x) __builtin_amdgcn_exp2f(x)
#else
#define EXP2F(x) __expf(0.6931471805599453f * (x))
#endif
#if __has_builtin(__builtin_amdgcn_rcpf)
#define RCPF(x) __builtin_amdgcn_rcpf(x)
#else
#define RCPF(x) (1.0f / (x))
#endif

__device__ __forceinline__ short f2bf(float x) {            // RNE fp32->bf16
    unsigned u = __float_as_uint(x);
    unsigned r = (u + 0x7FFFu + ((u >> 16) & 1u)) >> 16;
    return (short)r;
}
__device__ __forceinline__ float bf2f(short h) {
    return __uint_as_float(((unsigned)(unsigned short)h) << 16);
}
__device__ __forceinline__ float tanhfast(float x) {
    float e = __expf(2.0f * x);
    return 1.0f - 2.0f / (e + 1.0f);
}

// ---- workspace layout (bytes from d_ws base; all 16B-aligned) ----
#define WS_FRAGHI 0       // short[2*64*8]  = 2048 B
#define WS_FRAGLO 2048    // short[2*64*8]  = 2048 B
#define WS_ABK    4096    // float[256*20]  = 20480 B
#define WS_CF     24576   // float[256*20]  = 20480 B
#define WS_U      45056   // float[20]      = 80 B
#define WS_C0     45152   // float[1]
// total 45156 B

// One-block setup: builds lane-native weight fragments, per-z bias/cfeat
// tables, folded top-MLP vector u and constant C0. Kills all divergent
// gathers in the main kernel.
__global__ __launch_bounds__(256) void dtnn_setup(
    const float* __restrict__ Vw, const float* __restrict__ Vb,
    const float* __restrict__ emb,
    const float* __restrict__ W1, const float* __restrict__ b1,
    const float* __restrict__ W2, const float* __restrict__ b2,
    short* __restrict__ fragHi, short* __restrict__ fragLo,
    float* __restrict__ AbK, float* __restrict__ cfT,
    float* __restrict__ uT, float* __restrict__ C0out)
{
    const int tid = threadIdx.x;
    const float Kc = 2.8853900817779268f;   // 2*log2(e)

    // weight fragments in MFMA lane layout: [nt][lane][jj]
    if (tid < 64) {
        const int c16 = tid & 15, k0 = (tid >> 4) * 8;
        #pragma unroll
        for (int nt = 0; nt < 2; ++nt) {
            #pragma unroll
            for (int jj = 0; jj < 8; ++jj) {
                const int o = nt * 16 + c16, k = k0 + jj;
                float wvf = (o < Ee && k < Dd) ? Kc * Vw[o * 45 + 20 + k] : 0.0f;
                short h = f2bf(wvf);
                fragHi[(nt * 64 + tid) * 8 + jj] = h;
                fragLo[(nt * 64 + tid) * 8 + jj] = f2bf(wvf - bf2f(h));
            }
        }
    }
    // folded top MLP: u[o] = sum_p W2[p]*W1[p][o]; C0 = b2 + sum_p W2[p]*b1[p]
    if (tid < Ee) {
        float uo = 0.0f;
        #pragma unroll
        for (int p = 0; p < 10; ++p) uo = fmaf(W2[p], W1[p * Ee + tid], uo);
        uT[tid] = uo;
    }
    if (tid == 64) {
        float c0 = b2[0];
        #pragma unroll
        for (int p = 0; p < 10; ++p) c0 = fmaf(W2[p], b1[p], c0);
        C0out[0] = c0;
    }
    // per-z tables (depend only on the z VALUE): AbK[v][o], cf[v][o]
    const int v = tid;                       // 256 possible z values
    const float m = (v != 0) ? 1.0f : 0.0f;
    for (int o = 0; o < Ee; ++o) {
        float dot = 0.0f;
        #pragma unroll
        for (int f = 0; f < Ee; ++f)
            dot = fmaf(Vw[o * 45 + f], emb[v * Ee + f], dot);
        AbK[v * Ee + o] = Kc * (Vb[o] + m * dot);
        cfT[v * Ee + o] = m * emb[v * Ee + o];
    }
}

__global__ __launch_bounds__(256) void dtnn_kernel(
    const int*   __restrict__ z,      // [B,N]
    const float* __restrict__ dist,   // [B,N,N]
    const short* __restrict__ fragHi, // [2][64][8] lane-native
    const short* __restrict__ fragLo,
    const float* __restrict__ AbK,    // [256][20] by z-value
    const float* __restrict__ cfT,    // [256][20]
    const float* __restrict__ uT,     // [20]
    const float* __restrict__ C0p,    // [1]
    float*       __restrict__ out)    // [B]
{
    const int tid  = threadIdx.x;
    const int lane = tid & 63;
    const int wv   = blockIdx.x * 4 + (tid >> 6);  // global (b,i)
    const int b    = wv >> 8;
    const int i    = wv & 255;

    const int c16  = lane & 15;
    const int quad = lane >> 4;
    const int k0   = quad * 8;

    // dist row up-front: 4 coalesced b32 loads, lane l holds d[l + 64c]
    const float* drow = dist + (size_t)(b * Nn + i) * Nn;
    const float d0 = drow[lane];
    const float d1 = drow[lane + 64];
    const float d2 = drow[lane + 128];
    const float d3 = drow[lane + 192];

    // weight fragments: coalesced b128 loads in lane layout
    const short8* fH = (const short8*)fragHi;
    const short8* fL = (const short8*)fragLo;
    short8 whiK[2], wloK[2];
    whiK[0] = fH[lane];       whiK[1] = fH[64 + lane];
    wloK[0] = fL[lane];       wloK[1] = fL[64 + lane];

    const int   zi    = z[b * Nn + i];         // wave-uniform, 1 line
    const float maskv = (zi != 0) ? 1.0f : 0.0f;

    // per-lane bias & cfeat from per-z tables (2 cache lines per load)
    float AbKv[2], cfo[2];
    #pragma unroll
    for (int nt = 0; nt < 2; ++nt) {
        const int o = nt * 16 + c16;
        AbKv[nt] = (o < Ee) ? AbK[zi * Ee + o] : 0.0f;
        cfo[nt]  = (o < Ee) ? cfT[zi * Ee + o] : 0.0f;
    }

    // ---- main loop: 16 j-tiles; tanh-sum as  sum tanh = 256 - 2*sum sigma
    const float mu0 = 0.2f * (float)k0;
    const float CR  = 0.8521437889662113f;   // exp(-0.16)

    float R0 = 0.0f, R1 = 0.0f;

    #pragma unroll 4
    for (int t = 0; t < 16; ++t) {
        // d for my row j = t*16 + c16 via register bpermute (no global load)
        const int srcLane = 16 * (t & 3) + c16;
        float s01 = (t & 4) ? d1 : d0;
        float s23 = (t & 4) ? d3 : d2;
        float dv  = (t & 8) ? s23 : s01;
        const float d = __shfl(dv, srcLane, 64);

        // RBF recurrence in exp2 domain: g=exp(-2u^2), r=exp(0.8u-0.08)
        const float u = d - mu0;
        float g = EXP2F(-2.8853900817779268f * (u * u));
        float r = EXP2F(fmaf(1.1541560327111707f, u, -0.11541560327111707f));
        short8 ghi;
        #pragma unroll
        for (int jj = 0; jj < 8; ++jj) {
            if (jj) { g *= r; r *= CR; }
            ghi[jj] = f2bf(g);
        }

        floatx4 acc0 = {AbKv[0], AbKv[0], AbKv[0], AbKv[0]};
        floatx4 acc1 = {AbKv[1], AbKv[1], AbKv[1], AbKv[1]};
        acc0 = __builtin_amdgcn_mfma_f32_16x16x32_bf16(ghi, whiK[0], acc0, 0, 0, 0);
        acc0 = __builtin_amdgcn_mfma_f32_16x16x32_bf16(ghi, wloK[0], acc0, 0, 0, 0);
        acc1 = __builtin_amdgcn_mfma_f32_16x16x32_bf16(ghi, whiK[1], acc1, 0, 0, 0);
        acc1 = __builtin_amdgcn_mfma_f32_16x16x32_bf16(ghi, wloK[1], acc1, 0, 0, 0);

        // acc = 2*log2(e)*s  ->  sigma = 1/(2^acc + 1); tanh = 1 - 2*sigma
        #pragma unroll
        for (int reg = 0; reg < 4; ++reg) {
            R0 += RCPF(EXP2F(acc0[reg]) + 1.0f);
            R1 += RCPF(EXP2F(acc1[reg]) + 1.0f);
        }
    }

    // reduce sigma-sums over quads
    R0 += __shfl_xor(R0, 16, 64);
    R0 += __shfl_xor(R0, 32, 64);
    R1 += __shfl_xor(R1, 16, 64);
    R1 += __shfl_xor(R1, 32, 64);
    const float agg0 = 256.0f - 2.0f * R0;
    const float agg1 = 256.0f - 2.0f * R1;

    // epilogue: th = tanh(cfeat + mask*agg); e = sum_o u[o]*th[o]
    float e = 0.0f;
    #pragma unroll
    for (int nt = 0; nt < 2; ++nt) {
        const int o   = nt * 16 + c16;
        const float agg = (nt == 0) ? agg0 : agg1;
        const float th  = tanhfast(cfo[nt] + maskv * agg);
        const float uo  = (o < Ee) ? uT[o] : 0.0f;
        e = fmaf(th, uo, e);
    }
    e += __shfl_xor(e, 1, 64);
    e += __shfl_xor(e, 2, 64);
    e += __shfl_xor(e, 4, 64);
    e += __shfl_xor(e, 8, 64);

    if (lane == 0) atomicAdd(&out[b], e + C0p[0]);
}

extern "C" void kernel_launch(void* const* d_in, const int* in_sizes, int n_in,
                              void* d_out, int out_size, void* d_ws, size_t ws_size,
                              hipStream_t stream) {
    const int*   z    = (const int*)  d_in[0];
    const float* dist = (const float*)d_in[1];
    const float* emb  = (const float*)d_in[2];
    const float* Vw   = (const float*)d_in[3];
    const float* Vb   = (const float*)d_in[4];
    const float* W1   = (const float*)d_in[5];
    const float* b1   = (const float*)d_in[6];
    const float* W2   = (const float*)d_in[7];
    const float* b2   = (const float*)d_in[8];
    float* out = (float*)d_out;

    char* ws = (char*)d_ws;
    short* fragHi = (short*)(ws + WS_FRAGHI);
    short* fragLo = (short*)(ws + WS_FRAGLO);
    float* AbK    = (float*)(ws + WS_ABK);
    float* cfT    = (float*)(ws + WS_CF);
    float* uT     = (float*)(ws + WS_U);
    float* C0p    = (float*)(ws + WS_C0);

    hipMemsetAsync(out, 0, Bsz * sizeof(float), stream);

    dtnn_setup<<<1, 256, 0, stream>>>(Vw, Vb, emb, W1, b1, W2, b2,
                                      fragHi, fragLo, AbK, cfT, uT, C0p);

    // one wave per (b,i): B*N = 16384 waves, 4 waves/block -> 4096 blocks
    dtnn_kernel<<<Bsz * Nn / 4, 256, 0, stream>>>(
        z, dist, fragHi, fragLo, AbK, cfT, uT, C0p, out);
}

// Round 5
// 134.894 us; speedup vs baseline: 1.7300x; 1.7300x over previous
//
#include <hip/hip_runtime.h>

#define Bsz 64
#define Nn  256
#define Ee  20   // atom embedding dim
#define Dd  25   // gaussian centers

using short8  = __attribute__((ext_vector_type(8))) short;  // 8 bf16 (4 VGPRs)
using floatx4 = __attribute__((ext_vector_type(4))) float;  // 4 fp32 acc

#if __has_builtin(__builtin_amdgcn_exp2f)
#define EXP2F(x) __builtin_amdgcn_exp2f(x)
#else
#define EXP2F(x) __expf(0.6931471805599453f * (x))
#endif
#if __has_builtin(__builtin_amdgcn_rcpf)
#define RCPF(x) __builtin_amdgcn_rcpf(x)
#else
#define RCPF(x) (1.0f / (x))
#endif

__device__ __forceinline__ short f2bf(float x) {            // RNE fp32->bf16
    unsigned u = __float_as_uint(x);
    unsigned r = (u + 0x7FFFu + ((u >> 16) & 1u)) >> 16;
    return (short)r;
}
__device__ __forceinline__ float bf2f(short h) {
    return __uint_as_float(((unsigned)(unsigned short)h) << 16);
}
__device__ __forceinline__ float tanhfast(float x) {
    float e = __expf(2.0f * x);
    return 1.0f - 2.0f / (e + 1.0f);
}

// ---- workspace layout (bytes from d_ws base; all 16B-aligned) ----
#define WS_FRAGHI 0       // short[2*64*8]  = 2048 B
#define WS_FRAGLO 2048    // short[2*64*8]  = 2048 B
#define WS_ABK    4096    // float[256*20]  = 20480 B
#define WS_CF     24576   // float[256*20]  = 20480 B
#define WS_U      45056   // float[20]      = 80 B
#define WS_C0     45152   // float[1]
#define WS_PART   45184   // float[4096]    = 16384 B  (per-block partials)
// total 61568 B

// One-block setup: lane-native weight fragments, per-z bias/cfeat tables,
// folded top-MLP vector u and constant C0.
__global__ __launch_bounds__(256) void dtnn_setup(
    const float* __restrict__ Vw, const float* __restrict__ Vb,
    const float* __restrict__ emb,
    const float* __restrict__ W1, const float* __restrict__ b1,
    const float* __restrict__ W2, const float* __restrict__ b2,
    short* __restrict__ fragHi, short* __restrict__ fragLo,
    float* __restrict__ AbK, float* __restrict__ cfT,
    float* __restrict__ uT, float* __restrict__ C0out)
{
    const int tid = threadIdx.x;
    const float Kc = 2.8853900817779268f;   // 2*log2(e)

    if (tid < 64) {
        const int c16 = tid & 15, k0 = (tid >> 4) * 8;
        #pragma unroll
        for (int nt = 0; nt < 2; ++nt) {
            #pragma unroll
            for (int jj = 0; jj < 8; ++jj) {
                const int o = nt * 16 + c16, k = k0 + jj;
                float wvf = (o < Ee && k < Dd) ? Kc * Vw[o * 45 + 20 + k] : 0.0f;
                short h = f2bf(wvf);
                fragHi[(nt * 64 + tid) * 8 + jj] = h;
                fragLo[(nt * 64 + tid) * 8 + jj] = f2bf(wvf - bf2f(h));
            }
        }
    }
    if (tid < Ee) {
        float uo = 0.0f;
        #pragma unroll
        for (int p = 0; p < 10; ++p) uo = fmaf(W2[p], W1[p * Ee + tid], uo);
        uT[tid] = uo;
    }
    if (tid == 64) {
        float c0 = b2[0];
        #pragma unroll
        for (int p = 0; p < 10; ++p) c0 = fmaf(W2[p], b1[p], c0);
        C0out[0] = c0;
    }
    // per-z tables (depend only on the z VALUE)
    const int v = tid;
    const float m = (v != 0) ? 1.0f : 0.0f;
    for (int o = 0; o < Ee; ++o) {
        float dot = 0.0f;
        #pragma unroll
        for (int f = 0; f < Ee; ++f)
            dot = fmaf(Vw[o * 45 + f], emb[v * Ee + f], dot);
        AbK[v * Ee + o] = Kc * (Vb[o] + m * dot);
        cfT[v * Ee + o] = m * emb[v * Ee + o];
    }
}

__global__ __launch_bounds__(256) void dtnn_kernel(
    const int*   __restrict__ z,      // [B,N]
    const float* __restrict__ dist,   // [B,N,N]
    const short* __restrict__ fragHi, // [2][64][8] lane-native
    const short* __restrict__ fragLo,
    const float* __restrict__ AbK,    // [256][20] by z-value
    const float* __restrict__ cfT,    // [256][20]
    const float* __restrict__ uT,     // [20]
    float*       __restrict__ part)   // [4096] per-block partials
{
    const int tid  = threadIdx.x;
    const int lane = tid & 63;
    const int wave = tid >> 6;
    const int wv   = blockIdx.x * 4 + wave;  // global (b,i); all 4 share b
    const int b    = wv >> 8;
    const int i    = wv & 255;

    const int c16  = lane & 15;
    const int quad = lane >> 4;
    const int k0   = quad * 8;

    // dist row up-front: 4 coalesced b32 loads, lane l holds d[l + 64c]
    const float* drow = dist + (size_t)(b * Nn + i) * Nn;
    const float d0 = drow[lane];
    const float d1 = drow[lane + 64];
    const float d2 = drow[lane + 128];
    const float d3 = drow[lane + 192];

    // weight fragments: coalesced b128 loads in lane layout
    const short8* fH = (const short8*)fragHi;
    const short8* fL = (const short8*)fragLo;
    short8 whiK[2], wloK[2];
    whiK[0] = fH[lane];       whiK[1] = fH[64 + lane];
    wloK[0] = fL[lane];       wloK[1] = fL[64 + lane];

    const int   zi    = z[b * Nn + i];         // wave-uniform
    const float maskv = (zi != 0) ? 1.0f : 0.0f;

    float AbKv[2], cfo[2];
    #pragma unroll
    for (int nt = 0; nt < 2; ++nt) {
        const int o = nt * 16 + c16;
        AbKv[nt] = (o < Ee) ? AbK[zi * Ee + o] : 0.0f;
        cfo[nt]  = (o < Ee) ? cfT[zi * Ee + o] : 0.0f;
    }

    // ---- main loop: 16 j-tiles; tanh-sum as  sum tanh = 256 - 2*sum sigma
    const float mu0 = 0.2f * (float)k0;
    const float CR  = 0.8521437889662113f;   // exp(-0.16)

    float R0 = 0.0f, R1 = 0.0f;

    #pragma unroll 4
    for (int t = 0; t < 16; ++t) {
        // d for my row j = t*16 + c16 via register bpermute (no global load)
        const int srcLane = 16 * (t & 3) + c16;
        float s01 = (t & 4) ? d1 : d0;
        float s23 = (t & 4) ? d3 : d2;
        float dv  = (t & 8) ? s23 : s01;
        const float d = __shfl(dv, srcLane, 64);

        // RBF recurrence in exp2 domain: g=exp(-2u^2), r=exp(0.8u-0.08)
        const float u = d - mu0;
        float g = EXP2F(-2.8853900817779268f * (u * u));
        float r = EXP2F(fmaf(1.1541560327111707f, u, -0.11541560327111707f));
        short8 ghi;
        #pragma unroll
        for (int jj = 0; jj < 8; ++jj) {
            if (jj) { g *= r; r *= CR; }
            ghi[jj] = f2bf(g);
        }

        floatx4 acc0 = {AbKv[0], AbKv[0], AbKv[0], AbKv[0]};
        floatx4 acc1 = {AbKv[1], AbKv[1], AbKv[1], AbKv[1]};
        acc0 = __builtin_amdgcn_mfma_f32_16x16x32_bf16(ghi, whiK[0], acc0, 0, 0, 0);
        acc0 = __builtin_amdgcn_mfma_f32_16x16x32_bf16(ghi, wloK[0], acc0, 0, 0, 0);
        acc1 = __builtin_amdgcn_mfma_f32_16x16x32_bf16(ghi, whiK[1], acc1, 0, 0, 0);
        acc1 = __builtin_amdgcn_mfma_f32_16x16x32_bf16(ghi, wloK[1], acc1, 0, 0, 0);

        // acc = 2*log2(e)*s  ->  sigma = 1/(2^acc + 1); tanh = 1 - 2*sigma
        #pragma unroll
        for (int reg = 0; reg < 4; ++reg) {
            R0 += RCPF(EXP2F(acc0[reg]) + 1.0f);
            R1 += RCPF(EXP2F(acc1[reg]) + 1.0f);
        }
    }

    // reduce sigma-sums over quads
    R0 += __shfl_xor(R0, 16, 64);
    R0 += __shfl_xor(R0, 32, 64);
    R1 += __shfl_xor(R1, 16, 64);
    R1 += __shfl_xor(R1, 32, 64);
    const float agg0 = 256.0f - 2.0f * R0;
    const float agg1 = 256.0f - 2.0f * R1;

    // epilogue: th = tanh(cfeat + mask*agg); e = sum_o u[o]*th[o]
    float e = 0.0f;
    #pragma unroll
    for (int nt = 0; nt < 2; ++nt) {
        const int o   = nt * 16 + c16;
        const float agg = (nt == 0) ? agg0 : agg1;
        const float th  = tanhfast(cfo[nt] + maskv * agg);
        const float uo  = (o < Ee) ? uT[o] : 0.0f;
        e = fmaf(th, uo, e);
    }
    e += __shfl_xor(e, 1, 64);
    e += __shfl_xor(e, 2, 64);
    e += __shfl_xor(e, 4, 64);
    e += __shfl_xor(e, 8, 64);
    // all 64 lanes now hold this wave's atom-energy (minus C0)

    // block-level reduce: 4 waves -> one plain store (NO atomics)
    __shared__ float sE[4];
    if (lane == 0) sE[wave] = e;
    __syncthreads();
    if (tid == 0)
        part[blockIdx.x] = sE[0] + sE[1] + sE[2] + sE[3];
}

// 64 blocks x 64 lanes: out[b] = sum of 64 block-partials + 256*C0
__global__ __launch_bounds__(64) void dtnn_reduce(
    const float* __restrict__ part, const float* __restrict__ C0p,
    float* __restrict__ out)
{
    const int b = blockIdx.x;
    const int t = threadIdx.x;
    float v = part[b * 64 + t];
    v += __shfl_xor(v, 1, 64);
    v += __shfl_xor(v, 2, 64);
    v += __shfl_xor(v, 4, 64);
    v += __shfl_xor(v, 8, 64);
    v += __shfl_xor(v, 16, 64);
    v += __shfl_xor(v, 32, 64);
    if (t == 0) out[b] = v + 256.0f * C0p[0];
}

extern "C" void kernel_launch(void* const* d_in, const int* in_sizes, int n_in,
                              void* d_out, int out_size, void* d_ws, size_t ws_size,
                              hipStream_t stream) {
    const int*   z    = (const int*)  d_in[0];
    const float* dist = (const float*)d_in[1];
    const float* emb  = (const float*)d_in[2];
    const float* Vw   = (const float*)d_in[3];
    const float* Vb   = (const float*)d_in[4];
    const float* W1   = (const float*)d_in[5];
    const float* b1   = (const float*)d_in[6];
    const float* W2   = (const float*)d_in[7];
    const float* b2   = (const float*)d_in[8];
    float* out = (float*)d_out;

    char* ws = (char*)d_ws;
    short* fragHi = (short*)(ws + WS_FRAGHI);
    short* fragLo = (short*)(ws + WS_FRAGLO);
    float* AbK    = (float*)(ws + WS_ABK);
    float* cfT    = (float*)(ws + WS_CF);
    float* uT     = (float*)(ws + WS_U);
    float* C0p    = (float*)(ws + WS_C0);
    float* partP  = (float*)(ws + WS_PART);

    dtnn_setup<<<1, 256, 0, stream>>>(Vw, Vb, emb, W1, b1, W2, b2,
                                      fragHi, fragLo, AbK, cfT, uT, C0p);

    // one wave per (b,i): B*N = 16384 waves, 4 waves/block -> 4096 blocks
    dtnn_kernel<<<Bsz * Nn / 4, 256, 0, stream>>>(
        z, dist, fragHi, fragLo, AbK, cfT, uT, partP);

    // final: 64 partial-sums per batch -> out[b] (fully overwrites d_out)
    dtnn_reduce<<<Bsz, 64, 0, stream>>>(partP, C0p, out);
}